// Round 8
// baseline (2559.380 us; speedup 1.0000x reference)
//
#include <hip/hip_runtime.h>
#include <hip/hip_bf16.h>

#define NODES 100000
#define BN_EPS 1e-5f
#define NB2 128          // coarse buckets
#define NPB2 782         // nodes per bucket (128*782 = 100096 >= 100000)
#define CAP 25776        // slots per bucket (avg 25000, +4.9 sigma), 16-aligned
#define EPB 8192         // edges per place block (391 blocks at E=3.2M)

__device__ __forceinline__ unsigned bf16rne(float f) {
    unsigned u = __float_as_uint(f);
    u += 0x7FFFu + ((u >> 16) & 1u);
    return u >> 16;
}
__device__ __forceinline__ float bflo(unsigned u) { return __uint_as_float(u << 16); }
__device__ __forceinline__ float bfhi(unsigned u) { return __uint_as_float(u & 0xFFFF0000u); }

// ---------------------------------------------------------------------------
// init: cursor[b] = b*CAP, bn = 0.
// ---------------------------------------------------------------------------
__global__ __launch_bounds__(256) void k_init(int* __restrict__ cursor,
                                              float* __restrict__ bn) {
    const int t = threadIdx.x;
    if (t < NB2) cursor[t] = t * CAP;
    else if (t < NB2 + 128) bn[t - NB2] = 0.f;
}

// ---------------------------------------------------------------------------
// Placement into capacity-strided buckets. Per-wave LDS sub-hist -> one
// global claim per bucket -> per-wave cursors -> direct final-offset writes.
// packed[pos] = (rloc<<17)|g. 64 edges/bucket/block = 4 full lines.
// ---------------------------------------------------------------------------
__global__ __launch_bounds__(256) void k_place(
        const int* __restrict__ ridx, const int* __restrict__ gidx,
        int* __restrict__ cursor, unsigned* __restrict__ packed, int E) {
    __shared__ int lh[4][NB2];
    const int t = threadIdx.x;
    const int w = t >> 6;
    for (int k = t; k < 4 * NB2; k += 256) ((int*)lh)[k] = 0;
    __syncthreads();
    const int base = blockIdx.x * EPB;
    for (int k = 0; k < EPB / 256; ++k) {
        int e = base + t + k * 256;
        if (e < E) atomicAdd(&lh[w][(unsigned)ridx[e] / NPB2], 1);
    }
    __syncthreads();
    if (t < NB2) {
        int c0 = lh[0][t], c1 = lh[1][t], c2 = lh[2][t], c3 = lh[3][t];
        int tot = c0 + c1 + c2 + c3;
        if (tot) {
            int g0 = atomicAdd(&cursor[t], tot);
            lh[0][t] = g0;
            lh[1][t] = g0 + c0;
            lh[2][t] = g0 + c0 + c1;
            lh[3][t] = g0 + c0 + c1 + c2;
        }
    }
    __syncthreads();
    for (int k = 0; k < EPB / 256; ++k) {
        int e = base + t + k * 256;
        if (e < E) {
            unsigned r = (unsigned)ridx[e];
            unsigned b = r / NPB2;
            int off = atomicAdd(&lh[w][b], 1);
            if (off < (int)((b + 1) * CAP))   // capacity guard (P ~ 4e-5)
                packed[off] = ((r - b * NPB2) << 17) | (unsigned)gidx[e];
        }
    }
}

// ---------------------------------------------------------------------------
// Bucket sort, in place: block reads its <=CAP edges into registers, LDS
// hist(782)+scan, writes nodestart/cnt, scatters g back into its private
// L2-resident region in per-node order.
// ---------------------------------------------------------------------------
__global__ __launch_bounds__(1024) void k_sortb(
        const int* __restrict__ cursor, unsigned* __restrict__ packed,
        int* __restrict__ nodestart, int* __restrict__ cnt) {
    __shared__ int lh[1024];
    __shared__ int lsc[1024];
    const int b = blockIdx.x, t = threadIdx.x;
    const int s0b = b * CAP;
    int cntb = cursor[b] - s0b;
    if (cntb > CAP) cntb = CAP;
    unsigned r[(CAP + 1023) / 1024];  // 26
#pragma unroll
    for (int kk = 0; kk < (CAP + 1023) / 1024; ++kk) {
        int k = t + kk * 1024;
        if (k < cntb) r[kk] = packed[s0b + k];
    }
    lh[t] = 0;
    __syncthreads();
#pragma unroll
    for (int kk = 0; kk < (CAP + 1023) / 1024; ++kk) {
        int k = t + kk * 1024;
        if (k < cntb) atomicAdd(&lh[r[kk] >> 17], 1);
    }
    __syncthreads();
    lsc[t] = lh[t];
    __syncthreads();
    for (int off = 1; off < 1024; off <<= 1) {
        int v = lsc[t];
        int add = (t >= off) ? lsc[t - off] : 0;
        __syncthreads();
        lsc[t] = v + add;
        __syncthreads();
    }
    int excl = (t == 0) ? 0 : lsc[t - 1];
    if (t < NPB2) {
        int n = b * NPB2 + t;
        if (n < NODES) {
            nodestart[n] = s0b + excl;
            cnt[n] = lh[t];
        }
    }
    __syncthreads();
    lh[t] = excl;           // becomes scatter cursor
    __syncthreads();
#pragma unroll
    for (int kk = 0; kk < (CAP + 1023) / 1024; ++kk) {
        int k = t + kk * 1024;
        if (k < cntb) {
            unsigned v = r[kk];
            int pos = atomicAdd(&lh[v >> 17], 1);
            packed[s0b + pos] = v & 0x1FFFFu;
        }
    }
}

// ---------------------------------------------------------------------------
// GEMM -> packed-bf16 Fn. Weights in registers (global/L2), x tile in LDS
// read as float4 broadcasts (256 b128/wave instead of 2048 b32).
// ---------------------------------------------------------------------------
__global__ __launch_bounds__(256) void k_gemm_bf16(
        const float* __restrict__ x, const float* __restrict__ wn,
        unsigned* __restrict__ Fnh2) {
    __shared__ float lx[64 * 68];   // [ci][j], row stride 68 floats (17 f4)
    const int t = threadIdx.x;
    const int n0 = blockIdx.x * 64;
    for (int idx = t; idx < 4096; idx += 256) {
        int rr = idx >> 6, q = idx & 63;
        int n = n0 + q;
        lx[rr * 68 + q] = (n < NODES) ? x[rr * NODES + n] : 0.f;
    }
    const int c = t & 63;
    const int jb = t >> 6;
    float wreg[64];
    const float4* w4 = (const float4*)wn;
#pragma unroll
    for (int q = 0; q < 16; ++q) {
        float4 tmp = w4[c * 16 + q];
        wreg[4 * q] = tmp.x; wreg[4 * q + 1] = tmp.y;
        wreg[4 * q + 2] = tmp.z; wreg[4 * q + 3] = tmp.w;
    }
    __syncthreads();
    float accs[16];
#pragma unroll
    for (int q = 0; q < 16; ++q) accs[q] = 0.f;
    const float4* lx4 = (const float4*)lx;
#pragma unroll
    for (int ci = 0; ci < 64; ++ci) {
        float wv = wreg[ci];
        const float4* row = lx4 + ci * 17 + jb * 4;
        float4 a = row[0], bq = row[1], cq = row[2], dq = row[3];
        accs[0] += wv * a.x;  accs[1] += wv * a.y;
        accs[2] += wv * a.z;  accs[3] += wv * a.w;
        accs[4] += wv * bq.x; accs[5] += wv * bq.y;
        accs[6] += wv * bq.z; accs[7] += wv * bq.w;
        accs[8] += wv * cq.x; accs[9] += wv * cq.y;
        accs[10] += wv * cq.z; accs[11] += wv * cq.w;
        accs[12] += wv * dq.x; accs[13] += wv * dq.y;
        accs[14] += wv * dq.z; accs[15] += wv * dq.w;
    }
#pragma unroll
    for (int kk = 0; kk < 16; ++kk) {
        float v = accs[kk];
        float p = __shfl_xor(v, 1);
        int n = n0 + jb * 16 + kk;
        if (!(c & 1) && n < NODES)
            Fnh2[n * 32 + (c >> 1)] = bf16rne(v) | (bf16rne(p) << 16);
    }
}

// fp32 Fn variant (fallback path only)
__global__ __launch_bounds__(256) void k_gemm_n(
        const float* __restrict__ x, const float* __restrict__ wn,
        float* __restrict__ Fn) {
    __shared__ float lx[64][65];
    __shared__ float lw[64][65];
    const int t = threadIdx.x;
    const int n0 = blockIdx.x * 64;
    for (int idx = t; idx < 4096; idx += 256) {
        int r = idx >> 6, q = idx & 63;
        lw[r][q] = wn[idx];
        int n = n0 + q;
        lx[r][q] = (n < NODES) ? x[r * NODES + n] : 0.f;
    }
    __syncthreads();
    const int c = t & 63;
    const int jb = t >> 6;
    for (int k = 0; k < 16; ++k) {
        int j = jb + 4 * k;
        int n = n0 + j;
        if (n >= NODES) continue;
        float acc = 0.f;
#pragma unroll
        for (int ci = 0; ci < 64; ++ci)
            acc += lw[c][ci] * lx[ci][j];
        Fn[n * 64 + c] = acc;
    }
}

// ---------------------------------------------------------------------------
// Pull segment-mean: one wave per node, 2 edges per gather instruction
// (half-wave = 32 lanes x bf16x2 = one 128B row), 8 edges in flight.
// ---------------------------------------------------------------------------
__global__ __launch_bounds__(256) void k_segreduce(
        const unsigned* __restrict__ Fnh2, const unsigned* __restrict__ packed,
        const int* __restrict__ nodestart, const int* __restrict__ cnt,
        float2* __restrict__ mean2) {
    const int n = (int)((blockIdx.x * 256u + threadIdx.x) >> 6);
    if (n >= NODES) return;
    const int lane = threadIdx.x & 63;
    const int sub = lane >> 5;       // half-wave: which of the 2 edges
    const int cp = lane & 31;        // channel pair
    const int s0 = nodestart[n];
    const int cn = cnt[n];
    const int s1 = s0 + cn;
    float ax = 0.f, ay = 0.f;
    int i = s0;
    for (; i + 7 < s1; i += 8) {
        int g0 = (int)packed[i     + sub];
        int g1 = (int)packed[i + 2 + sub];
        int g2 = (int)packed[i + 4 + sub];
        int g3 = (int)packed[i + 6 + sub];
        unsigned u0 = Fnh2[g0 * 32 + cp];
        unsigned u1 = Fnh2[g1 * 32 + cp];
        unsigned u2 = Fnh2[g2 * 32 + cp];
        unsigned u3 = Fnh2[g3 * 32 + cp];
        ax += bflo(u0) + bflo(u1) + bflo(u2) + bflo(u3);
        ay += bfhi(u0) + bfhi(u1) + bfhi(u2) + bfhi(u3);
    }
    for (; i < s1; i += 2) {
        if (i + sub < s1) {
            unsigned u = Fnh2[(int)packed[i + sub] * 32 + cp];
            ax += bflo(u);
            ay += bfhi(u);
        }
    }
    ax += __shfl_xor(ax, 32);
    ay += __shfl_xor(ay, 32);
    if (sub == 0) {
        float inv = 1.f / fmaxf((float)cn, 1.f);
        float2 m; m.x = ax * inv; m.y = ay * inv;
        mean2[n * 32 + cp] = m;
    }
}

// ---------------------------------------------------------------------------
// Combine: Fv GEMM (register weights + f4 LDS), add mean (pre-divided; or
// sums/cnt in fallback), transpose via LDS tile to [c][n], BN partials.
// ---------------------------------------------------------------------------
__global__ __launch_bounds__(256) void k_combine(
        const float* __restrict__ x, const float* __restrict__ wv,
        const float* __restrict__ sums, const int* __restrict__ counts,
        const int divide,
        float* __restrict__ outpre, float* __restrict__ bn) {
    __shared__ float lx[64 * 68];
    __shared__ float tile[64 * 65];
    __shared__ float reds[64][4];
    __shared__ float redq[64][4];
    const int t = threadIdx.x;
    const int n0 = blockIdx.x * 64;
    for (int idx = t; idx < 4096; idx += 256) {
        int rr = idx >> 6, q = idx & 63;
        int n = n0 + q;
        lx[rr * 68 + q] = (n < NODES) ? x[rr * NODES + n] : 0.f;
    }
    const int c = t & 63;
    const int jb = t >> 6;
    float wreg[64];
    const float4* w4 = (const float4*)wv;
#pragma unroll
    for (int q = 0; q < 16; ++q) {
        float4 tmp = w4[c * 16 + q];
        wreg[4 * q] = tmp.x; wreg[4 * q + 1] = tmp.y;
        wreg[4 * q + 2] = tmp.z; wreg[4 * q + 3] = tmp.w;
    }
    __syncthreads();
    float accs[16];
#pragma unroll
    for (int q = 0; q < 16; ++q) accs[q] = 0.f;
    const float4* lx4 = (const float4*)lx;
#pragma unroll
    for (int ci = 0; ci < 64; ++ci) {
        float wvv = wreg[ci];
        const float4* row = lx4 + ci * 17 + jb * 4;
        float4 a = row[0], bq = row[1], cq = row[2], dq = row[3];
        accs[0] += wvv * a.x;  accs[1] += wvv * a.y;
        accs[2] += wvv * a.z;  accs[3] += wvv * a.w;
        accs[4] += wvv * bq.x; accs[5] += wvv * bq.y;
        accs[6] += wvv * bq.z; accs[7] += wvv * bq.w;
        accs[8] += wvv * cq.x; accs[9] += wvv * cq.y;
        accs[10] += wvv * cq.z; accs[11] += wvv * cq.w;
        accs[12] += wvv * dq.x; accs[13] += wvv * dq.y;
        accs[14] += wvv * dq.z; accs[15] += wvv * dq.w;
    }
    float ls = 0.f, lq = 0.f;
#pragma unroll
    for (int kk = 0; kk < 16; ++kk) {
        int j = jb * 16 + kk;
        int n = n0 + j;
        float v = 0.f;
        if (n < NODES) {
            float m = sums[n * 64 + c];
            if (divide) m /= fmaxf((float)counts[n], 1.f);
            v = m + accs[kk];
            ls += v;
            lq += v * v;
        }
        tile[c * 65 + j] = v;
    }
    reds[c][jb] = ls;
    redq[c][jb] = lq;
    __syncthreads();
    const int j2 = t & 63;
    const int c2 = t >> 6;
    const int n = n0 + j2;
    if (n < NODES) {
        for (int k = 0; k < 16; ++k) {
            int cc = c2 + 4 * k;
            outpre[cc * NODES + n] = tile[cc * 65 + j2];
        }
    }
    if (t < 64) {
        atomicAdd(&bn[t],      reds[t][0] + reds[t][1] + reds[t][2] + reds[t][3]);
        atomicAdd(&bn[64 + t], redq[t][0] + redq[t][1] + redq[t][2] + redq[t][3]);
    }
}

// K4: per-channel affine from batch stats + PReLU, in place on d_out [C][N].
__global__ __launch_bounds__(256) void k_final(
        float* __restrict__ out, const float* __restrict__ bn,
        const float* __restrict__ gamma, const float* __restrict__ beta,
        const float* __restrict__ pa) {
    const int c = blockIdx.y;
    const int n = blockIdx.x * 256 + threadIdx.x;
    const float invN = 1.f / (float)NODES;
    float mu = bn[c] * invN;
    float var = fmaxf(bn[64 + c] * invN - mu * mu, 0.f);
    float scale = gamma[c] * rsqrtf(var + BN_EPS);
    float shift = beta[c] - mu * scale;
    float a = pa[0];
    if (n < NODES) {
        float y = out[c * NODES + n] * scale + shift;
        y = (y >= 0.f) ? y : a * y;
        out[c * NODES + n] = y;
    }
}

// Fallback (ws too small): round-2 atomic scatter, proven correct.
__global__ __launch_bounds__(256) void k_scatter(
        const float* __restrict__ Fn,
        const int* __restrict__ gidx, const int* __restrict__ ridx,
        float* __restrict__ sums, int* __restrict__ counts, int E) {
    const int wave = (int)((blockIdx.x * blockDim.x + threadIdx.x) >> 6);
    const int lane = threadIdx.x & 63;
    const int base = wave * 64;
    if (base >= E) return;
    const int nvalid = min(64, E - base);
    int g = 0, r = 0;
    if (lane < nvalid) {
        g = gidx[base + lane];
        r = ridx[base + lane];
        atomicAdd(&counts[r], 1);
    }
    for (int i = 0; i < nvalid; ++i) {
        int gg = __shfl(g, i);
        int rr = __shfl(r, i);
        float v = Fn[gg * 64 + lane];
        atomicAdd(&sums[rr * 64 + lane], v);
    }
}

extern "C" void kernel_launch(void* const* d_in, const int* in_sizes, int n_in,
                              void* d_out, int out_size, void* d_ws, size_t ws_size,
                              hipStream_t stream) {
    const float* x     = (const float*)d_in[0];
    const float* w_v   = (const float*)d_in[1];
    const float* w_n   = (const float*)d_in[2];
    const float* gamma = (const float*)d_in[3];
    const float* beta  = (const float*)d_in[4];
    const float* pa    = (const float*)d_in[5];
    const int* ridx    = (const int*)d_in[6];
    const int* gidx    = (const int*)d_in[7];
    float* out = (float*)d_out;

    const int E = in_sizes[6];
    const long long N64 = (long long)NODES * 64;
    const int ntiles = (NODES + 63) / 64;
    const dim3 g4((NODES + 255) / 256, 64);

    // Main ws (words): mean[N64] | packed[128*CAP] | cursor[128] | bn[128] |
    //                  nodestart[NODES] | cnt[NODES]   = 9,899,584 (39.6 MB)
    size_t need = ((size_t)N64 + (size_t)NB2 * CAP + NB2 + 128
                   + NODES + NODES) * 4;

    if (ws_size >= need) {
        float*    mean      = (float*)d_ws;
        unsigned* packed    = (unsigned*)(mean + N64);
        int*      cursor    = (int*)(packed + (size_t)NB2 * CAP);
        float*    bn        = (float*)(cursor + NB2);
        int*      nodestart = (int*)(bn + 128);
        int*      cntarr    = nodestart + NODES;
        unsigned* Fnh2 = (unsigned*)out;  // 12.8 MB staged in d_out

        k_init<<<1, 256, 0, stream>>>(cursor, bn);
        k_place<<<(E + EPB - 1) / EPB, 256, 0, stream>>>(ridx, gidx, cursor,
                                                         packed, E);
        k_sortb<<<NB2, 1024, 0, stream>>>(cursor, packed, nodestart, cntarr);
        k_gemm_bf16<<<ntiles, 256, 0, stream>>>(x, w_n, Fnh2);
        k_segreduce<<<(NODES * 64 + 255) / 256, 256, 0, stream>>>(
            Fnh2, packed, nodestart, cntarr, (float2*)mean);
        k_combine<<<ntiles, 256, 0, stream>>>(x, w_v, mean, cntarr, 0, out, bn);
        k_final<<<g4, 256, 0, stream>>>(out, bn, gamma, beta, pa);
    } else {
        // Fallback: atomic-scatter path (26.0 MB ws).
        float* sums   = (float*)d_ws;
        int*   counts = (int*)(sums + N64);
        float* bn     = (float*)(sums + N64 + NODES);
        float* Fn = out;

        hipMemsetAsync(sums, 0, (size_t)(N64 + NODES + 128) * sizeof(float),
                       stream);
        k_gemm_n<<<ntiles, 256, 0, stream>>>(x, w_n, Fn);
        k_scatter<<<(E + 255) / 256, 256, 0, stream>>>(Fn, gidx, ridx, sums,
                                                       counts, E);
        k_combine<<<ntiles, 256, 0, stream>>>(x, w_v, sums, counts, 1, out, bn);
        k_final<<<g4, 256, 0, stream>>>(out, bn, gamma, beta, pa);
    }
}

// Round 9
// 661.958 us; speedup vs baseline: 3.8664x; 3.8664x over previous
//
#include <hip/hip_runtime.h>
#include <hip/hip_bf16.h>

#define NODES 100000
#define BN_EPS 1e-5f
#define NB2 128          // coarse buckets
#define NPB2 782         // nodes per bucket (128*782 = 100096 >= 100000)
#define CAP 25776        // slots per bucket (avg 25000, +4.9 sigma), 16-aligned
#define EPB 8192         // edges per place block (391 blocks at E=3.2M)

__device__ __forceinline__ unsigned bf16rne(float f) {
    unsigned u = __float_as_uint(f);
    u += 0x7FFFu + ((u >> 16) & 1u);
    return u >> 16;
}
__device__ __forceinline__ float bflo(unsigned u) { return __uint_as_float(u << 16); }
__device__ __forceinline__ float bfhi(unsigned u) { return __uint_as_float(u & 0xFFFF0000u); }

// ---------------------------------------------------------------------------
// init: cursor[b] = b*CAP, bn = 0.
// ---------------------------------------------------------------------------
__global__ __launch_bounds__(256) void k_init(int* __restrict__ cursor,
                                              float* __restrict__ bn) {
    const int t = threadIdx.x;
    if (t < NB2) cursor[t] = t * CAP;
    else if (t < NB2 + 128) bn[t - NB2] = 0.f;
}

// ---------------------------------------------------------------------------
// Placement into capacity-strided buckets (no hist/scan prepass needed).
// ---------------------------------------------------------------------------
__global__ __launch_bounds__(256) void k_place(
        const int* __restrict__ ridx, const int* __restrict__ gidx,
        int* __restrict__ cursor, unsigned* __restrict__ packed, int E) {
    __shared__ int lh[4][NB2];
    const int t = threadIdx.x;
    const int w = t >> 6;
    for (int k = t; k < 4 * NB2; k += 256) ((int*)lh)[k] = 0;
    __syncthreads();
    const int base = blockIdx.x * EPB;
    for (int k = 0; k < EPB / 256; ++k) {
        int e = base + t + k * 256;
        if (e < E) atomicAdd(&lh[w][(unsigned)ridx[e] / NPB2], 1);
    }
    __syncthreads();
    if (t < NB2) {
        int c0 = lh[0][t], c1 = lh[1][t], c2 = lh[2][t], c3 = lh[3][t];
        int tot = c0 + c1 + c2 + c3;
        if (tot) {
            int g0 = atomicAdd(&cursor[t], tot);
            lh[0][t] = g0;
            lh[1][t] = g0 + c0;
            lh[2][t] = g0 + c0 + c1;
            lh[3][t] = g0 + c0 + c1 + c2;
        }
    }
    __syncthreads();
    for (int k = 0; k < EPB / 256; ++k) {
        int e = base + t + k * 256;
        if (e < E) {
            unsigned r = (unsigned)ridx[e];
            unsigned b = r / NPB2;
            int off = atomicAdd(&lh[w][b], 1);
            if (off < (int)((b + 1) * CAP))   // capacity guard (P ~ 4e-5)
                packed[off] = ((r - b * NPB2) << 17) | (unsigned)gidx[e];
        }
    }
}

// ---------------------------------------------------------------------------
// Bucket sort, in place within the bucket's private L2-resident region.
// ---------------------------------------------------------------------------
__global__ __launch_bounds__(1024) void k_sortb(
        const int* __restrict__ cursor, unsigned* __restrict__ packed,
        int* __restrict__ nodestart, int* __restrict__ cnt) {
    __shared__ int lh[1024];
    __shared__ int lsc[1024];
    const int b = blockIdx.x, t = threadIdx.x;
    const int s0b = b * CAP;
    int cntb = cursor[b] - s0b;
    if (cntb > CAP) cntb = CAP;
    unsigned r[(CAP + 1023) / 1024];  // 26, statically indexed
#pragma unroll
    for (int kk = 0; kk < (CAP + 1023) / 1024; ++kk) {
        int k = t + kk * 1024;
        if (k < cntb) r[kk] = packed[s0b + k];
    }
    lh[t] = 0;
    __syncthreads();
#pragma unroll
    for (int kk = 0; kk < (CAP + 1023) / 1024; ++kk) {
        int k = t + kk * 1024;
        if (k < cntb) atomicAdd(&lh[r[kk] >> 17], 1);
    }
    __syncthreads();
    lsc[t] = lh[t];
    __syncthreads();
    for (int off = 1; off < 1024; off <<= 1) {
        int v = lsc[t];
        int add = (t >= off) ? lsc[t - off] : 0;
        __syncthreads();
        lsc[t] = v + add;
        __syncthreads();
    }
    int excl = (t == 0) ? 0 : lsc[t - 1];
    if (t < NPB2) {
        int n = b * NPB2 + t;
        if (n < NODES) {
            nodestart[n] = s0b + excl;
            cnt[n] = lh[t];
        }
    }
    __syncthreads();
    lh[t] = excl;           // becomes scatter cursor
    __syncthreads();
#pragma unroll
    for (int kk = 0; kk < (CAP + 1023) / 1024; ++kk) {
        int k = t + kk * 1024;
        if (k < cntb) {
            unsigned v = r[kk];
            int pos = atomicAdd(&lh[v >> 17], 1);
            packed[s0b + pos] = v & 0x1FFFFu;
        }
    }
}

// ---------------------------------------------------------------------------
// GEMM -> packed-bf16 Fn. Register-lean 4x4 blocking: thread = 4 channels x
// 4 nodes, both operands via ds_read_b128 from LDS (x tile + transposed w).
// acc[16] + 2 float4 temps: no spill (round-8 lesson: wreg[64] spilled).
// ---------------------------------------------------------------------------
__global__ __launch_bounds__(256) void k_gemm_bf16(
        const float* __restrict__ x, const float* __restrict__ wn,
        unsigned* __restrict__ Fnh2) {
    __shared__ float lx[64 * 68];   // [ci][j],  row stride 68 (16B-aligned)
    __shared__ float wt[64 * 68];   // [ci][co], transposed weights
    const int t = threadIdx.x;
    const int n0 = blockIdx.x * 64;
    for (int idx = t; idx < 4096; idx += 256) {
        int rr = idx >> 6, q = idx & 63;
        int n = n0 + q;
        lx[rr * 68 + q] = (n < NODES) ? x[rr * NODES + n] : 0.f;
        wt[q * 68 + rr] = wn[idx];   // wn[co=rr][ci=q] -> wt[ci=q][co=rr]
    }
    __syncthreads();
    const int c4 = (t & 15) * 4;    // 4 consecutive output channels
    const int j4 = (t >> 4) * 4;    // 4 consecutive nodes
    float4 a0 = {0,0,0,0}, a1 = {0,0,0,0}, a2 = {0,0,0,0}, a3 = {0,0,0,0};
#pragma unroll
    for (int ci = 0; ci < 64; ++ci) {
        float4 w = *(const float4*)&wt[ci * 68 + c4];
        float4 xv = *(const float4*)&lx[ci * 68 + j4];
        a0.x += w.x * xv.x; a0.y += w.x * xv.y; a0.z += w.x * xv.z; a0.w += w.x * xv.w;
        a1.x += w.y * xv.x; a1.y += w.y * xv.y; a1.z += w.y * xv.z; a1.w += w.y * xv.w;
        a2.x += w.z * xv.x; a2.y += w.z * xv.y; a2.z += w.z * xv.z; a2.w += w.z * xv.w;
        a3.x += w.w * xv.x; a3.y += w.w * xv.y; a3.z += w.w * xv.z; a3.w += w.w * xv.w;
    }
    uint2* F2 = (uint2*)Fnh2;
#pragma unroll
    for (int k = 0; k < 4; ++k) {
        int n = n0 + j4 + k;
        if (n < NODES) {
            float v0 = (k == 0) ? a0.x : (k == 1) ? a0.y : (k == 2) ? a0.z : a0.w;
            float v1 = (k == 0) ? a1.x : (k == 1) ? a1.y : (k == 2) ? a1.z : a1.w;
            float v2 = (k == 0) ? a2.x : (k == 1) ? a2.y : (k == 2) ? a2.z : a2.w;
            float v3 = (k == 0) ? a3.x : (k == 1) ? a3.y : (k == 2) ? a3.z : a3.w;
            uint2 val;
            val.x = bf16rne(v0) | (bf16rne(v1) << 16);
            val.y = bf16rne(v2) | (bf16rne(v3) << 16);
            F2[n * 16 + (c4 >> 2)] = val;   // 128B contiguous across 16 lanes
        }
    }
}

// fp32 Fn variant (fallback path only)
__global__ __launch_bounds__(256) void k_gemm_n(
        const float* __restrict__ x, const float* __restrict__ wn,
        float* __restrict__ Fn) {
    __shared__ float lx[64][65];
    __shared__ float lw[64][65];
    const int t = threadIdx.x;
    const int n0 = blockIdx.x * 64;
    for (int idx = t; idx < 4096; idx += 256) {
        int r = idx >> 6, q = idx & 63;
        lw[r][q] = wn[idx];
        int n = n0 + q;
        lx[r][q] = (n < NODES) ? x[r * NODES + n] : 0.f;
    }
    __syncthreads();
    const int c = t & 63;
    const int jb = t >> 6;
    for (int k = 0; k < 16; ++k) {
        int j = jb + 4 * k;
        int n = n0 + j;
        if (n >= NODES) continue;
        float acc = 0.f;
#pragma unroll
        for (int ci = 0; ci < 64; ++ci)
            acc += lw[c][ci] * lx[ci][j];
        Fn[n * 64 + c] = acc;
    }
}

// ---------------------------------------------------------------------------
// Pull segment-mean: one wave per node, 2 edges per gather instruction.
// ---------------------------------------------------------------------------
__global__ __launch_bounds__(256) void k_segreduce(
        const unsigned* __restrict__ Fnh2, const unsigned* __restrict__ packed,
        const int* __restrict__ nodestart, const int* __restrict__ cnt,
        float2* __restrict__ mean2) {
    const int n = (int)((blockIdx.x * 256u + threadIdx.x) >> 6);
    if (n >= NODES) return;
    const int lane = threadIdx.x & 63;
    const int sub = lane >> 5;
    const int cp = lane & 31;
    const int s0 = nodestart[n];
    const int cn = cnt[n];
    const int s1 = s0 + cn;
    float ax = 0.f, ay = 0.f;
    int i = s0;
    for (; i + 7 < s1; i += 8) {
        int g0 = (int)packed[i     + sub];
        int g1 = (int)packed[i + 2 + sub];
        int g2 = (int)packed[i + 4 + sub];
        int g3 = (int)packed[i + 6 + sub];
        unsigned u0 = Fnh2[g0 * 32 + cp];
        unsigned u1 = Fnh2[g1 * 32 + cp];
        unsigned u2 = Fnh2[g2 * 32 + cp];
        unsigned u3 = Fnh2[g3 * 32 + cp];
        ax += bflo(u0) + bflo(u1) + bflo(u2) + bflo(u3);
        ay += bfhi(u0) + bfhi(u1) + bfhi(u2) + bfhi(u3);
    }
    for (; i < s1; i += 2) {
        if (i + sub < s1) {
            unsigned u = Fnh2[(int)packed[i + sub] * 32 + cp];
            ax += bflo(u);
            ay += bfhi(u);
        }
    }
    ax += __shfl_xor(ax, 32);
    ay += __shfl_xor(ay, 32);
    if (sub == 0) {
        float inv = 1.f / fmaxf((float)cn, 1.f);
        float2 m; m.x = ax * inv; m.y = ay * inv;
        mean2[n * 32 + cp] = m;
    }
}

// ---------------------------------------------------------------------------
// Combine: Fv GEMM (4x4 blocking, b128 LDS), + mean (float4 coalesced),
// BN partials, LDS transpose to [c][n]. tile aliases dead wt buffer.
// ---------------------------------------------------------------------------
__global__ __launch_bounds__(256) void k_combine(
        const float* __restrict__ x, const float* __restrict__ wv,
        const float* __restrict__ sums, const int* __restrict__ counts,
        const int divide,
        float* __restrict__ outpre, float* __restrict__ bn) {
    __shared__ float lx[64 * 68];
    __shared__ float wt[64 * 68];   // reused as tile[c*65+j] after FMA loop
    __shared__ float reds[64][16];
    __shared__ float redq[64][16];
    const int t = threadIdx.x;
    const int n0 = blockIdx.x * 64;
    for (int idx = t; idx < 4096; idx += 256) {
        int rr = idx >> 6, q = idx & 63;
        int n = n0 + q;
        lx[rr * 68 + q] = (n < NODES) ? x[rr * NODES + n] : 0.f;
        wt[q * 68 + rr] = wv[idx];
    }
    __syncthreads();
    const int c4 = (t & 15) * 4;
    const int j4 = (t >> 4) * 4;
    float4 a0 = {0,0,0,0}, a1 = {0,0,0,0}, a2 = {0,0,0,0}, a3 = {0,0,0,0};
#pragma unroll
    for (int ci = 0; ci < 64; ++ci) {
        float4 w = *(const float4*)&wt[ci * 68 + c4];
        float4 xv = *(const float4*)&lx[ci * 68 + j4];
        a0.x += w.x * xv.x; a0.y += w.x * xv.y; a0.z += w.x * xv.z; a0.w += w.x * xv.w;
        a1.x += w.y * xv.x; a1.y += w.y * xv.y; a1.z += w.y * xv.z; a1.w += w.y * xv.w;
        a2.x += w.z * xv.x; a2.y += w.z * xv.y; a2.z += w.z * xv.z; a2.w += w.z * xv.w;
        a3.x += w.w * xv.x; a3.y += w.w * xv.y; a3.z += w.w * xv.z; a3.w += w.w * xv.w;
    }
    __syncthreads();                 // wt is dead for ALL waves; reuse as tile
    float* tile = wt;
    float ls0 = 0.f, ls1 = 0.f, ls2 = 0.f, ls3 = 0.f;
    float lq0 = 0.f, lq1 = 0.f, lq2 = 0.f, lq3 = 0.f;
    const float4* sums4 = (const float4*)sums;
#pragma unroll
    for (int k = 0; k < 4; ++k) {
        int j = j4 + k;
        int n = n0 + j;
        float v0 = 0.f, v1 = 0.f, v2 = 0.f, v3 = 0.f;
        if (n < NODES) {
            float4 mv = sums4[n * 16 + (c4 >> 2)];
            if (divide) {
                float cf = fmaxf((float)counts[n], 1.f);
                mv.x /= cf; mv.y /= cf; mv.z /= cf; mv.w /= cf;
            }
            float b0 = (k == 0) ? a0.x : (k == 1) ? a0.y : (k == 2) ? a0.z : a0.w;
            float b1 = (k == 0) ? a1.x : (k == 1) ? a1.y : (k == 2) ? a1.z : a1.w;
            float b2 = (k == 0) ? a2.x : (k == 1) ? a2.y : (k == 2) ? a2.z : a2.w;
            float b3 = (k == 0) ? a3.x : (k == 1) ? a3.y : (k == 2) ? a3.z : a3.w;
            v0 = mv.x + b0; v1 = mv.y + b1; v2 = mv.z + b2; v3 = mv.w + b3;
            ls0 += v0; lq0 += v0 * v0;
            ls1 += v1; lq1 += v1 * v1;
            ls2 += v2; lq2 += v2 * v2;
            ls3 += v3; lq3 += v3 * v3;
        }
        tile[(c4 + 0) * 65 + j] = v0;
        tile[(c4 + 1) * 65 + j] = v1;
        tile[(c4 + 2) * 65 + j] = v2;
        tile[(c4 + 3) * 65 + j] = v3;
    }
    const int jg = t >> 4;
    reds[c4 + 0][jg] = ls0; redq[c4 + 0][jg] = lq0;
    reds[c4 + 1][jg] = ls1; redq[c4 + 1][jg] = lq1;
    reds[c4 + 2][jg] = ls2; redq[c4 + 2][jg] = lq2;
    reds[c4 + 3][jg] = ls3; redq[c4 + 3][jg] = lq3;
    __syncthreads();
    const int j2 = t & 63;
    const int c2 = t >> 6;
    const int n = n0 + j2;
    if (n < NODES) {
        for (int k = 0; k < 16; ++k) {
            int cc = c2 + 4 * k;
            outpre[cc * NODES + n] = tile[cc * 65 + j2];
        }
    }
    if (t < 64) {
        float s = 0.f, q = 0.f;
#pragma unroll
        for (int k = 0; k < 16; ++k) { s += reds[t][k]; q += redq[t][k]; }
        atomicAdd(&bn[t], s);
        atomicAdd(&bn[64 + t], q);
    }
}

// K4: per-channel affine from batch stats + PReLU, in place on d_out [C][N].
__global__ __launch_bounds__(256) void k_final(
        float* __restrict__ out, const float* __restrict__ bn,
        const float* __restrict__ gamma, const float* __restrict__ beta,
        const float* __restrict__ pa) {
    const int c = blockIdx.y;
    const int n = blockIdx.x * 256 + threadIdx.x;
    const float invN = 1.f / (float)NODES;
    float mu = bn[c] * invN;
    float var = fmaxf(bn[64 + c] * invN - mu * mu, 0.f);
    float scale = gamma[c] * rsqrtf(var + BN_EPS);
    float shift = beta[c] - mu * scale;
    float a = pa[0];
    if (n < NODES) {
        float y = out[c * NODES + n] * scale + shift;
        y = (y >= 0.f) ? y : a * y;
        out[c * NODES + n] = y;
    }
}

// Fallback (ws too small): round-2 atomic scatter, proven correct.
__global__ __launch_bounds__(256) void k_scatter(
        const float* __restrict__ Fn,
        const int* __restrict__ gidx, const int* __restrict__ ridx,
        float* __restrict__ sums, int* __restrict__ counts, int E) {
    const int wave = (int)((blockIdx.x * blockDim.x + threadIdx.x) >> 6);
    const int lane = threadIdx.x & 63;
    const int base = wave * 64;
    if (base >= E) return;
    const int nvalid = min(64, E - base);
    int g = 0, r = 0;
    if (lane < nvalid) {
        g = gidx[base + lane];
        r = ridx[base + lane];
        atomicAdd(&counts[r], 1);
    }
    for (int i = 0; i < nvalid; ++i) {
        int gg = __shfl(g, i);
        int rr = __shfl(r, i);
        float v = Fn[gg * 64 + lane];
        atomicAdd(&sums[rr * 64 + lane], v);
    }
}

extern "C" void kernel_launch(void* const* d_in, const int* in_sizes, int n_in,
                              void* d_out, int out_size, void* d_ws, size_t ws_size,
                              hipStream_t stream) {
    const float* x     = (const float*)d_in[0];
    const float* w_v   = (const float*)d_in[1];
    const float* w_n   = (const float*)d_in[2];
    const float* gamma = (const float*)d_in[3];
    const float* beta  = (const float*)d_in[4];
    const float* pa    = (const float*)d_in[5];
    const int* ridx    = (const int*)d_in[6];
    const int* gidx    = (const int*)d_in[7];
    float* out = (float*)d_out;

    const int E = in_sizes[6];
    const long long N64 = (long long)NODES * 64;
    const int ntiles = (NODES + 63) / 64;
    const dim3 g4((NODES + 255) / 256, 64);

    // Main ws (words): mean[N64] | packed[128*CAP] | cursor[128] | bn[128] |
    //                  nodestart[NODES] | cnt[NODES]   = 9,899,584 (39.6 MB)
    size_t need = ((size_t)N64 + (size_t)NB2 * CAP + NB2 + 128
                   + NODES + NODES) * 4;

    if (ws_size >= need) {
        float*    mean      = (float*)d_ws;
        unsigned* packed    = (unsigned*)(mean + N64);
        int*      cursor    = (int*)(packed + (size_t)NB2 * CAP);
        float*    bn        = (float*)(cursor + NB2);
        int*      nodestart = (int*)(bn + 128);
        int*      cntarr    = nodestart + NODES;
        unsigned* Fnh2 = (unsigned*)out;  // 12.8 MB staged in d_out

        k_init<<<1, 256, 0, stream>>>(cursor, bn);
        k_place<<<(E + EPB - 1) / EPB, 256, 0, stream>>>(ridx, gidx, cursor,
                                                         packed, E);
        k_sortb<<<NB2, 1024, 0, stream>>>(cursor, packed, nodestart, cntarr);
        k_gemm_bf16<<<ntiles, 256, 0, stream>>>(x, w_n, Fnh2);
        k_segreduce<<<(NODES * 64 + 255) / 256, 256, 0, stream>>>(
            Fnh2, packed, nodestart, cntarr, (float2*)mean);
        k_combine<<<ntiles, 256, 0, stream>>>(x, w_v, mean, cntarr, 0, out, bn);
        k_final<<<g4, 256, 0, stream>>>(out, bn, gamma, beta, pa);
    } else {
        // Fallback: atomic-scatter path (26.0 MB ws).
        float* sums   = (float*)d_ws;
        int*   counts = (int*)(sums + N64);
        float* bn     = (float*)(sums + N64 + NODES);
        float* Fn = out;

        hipMemsetAsync(sums, 0, (size_t)(N64 + NODES + 128) * sizeof(float),
                       stream);
        k_gemm_n<<<ntiles, 256, 0, stream>>>(x, w_n, Fn);
        k_scatter<<<(E + 255) / 256, 256, 0, stream>>>(Fn, gidx, ridx, sums,
                                                       counts, E);
        k_combine<<<ntiles, 256, 0, stream>>>(x, w_v, sums, counts, 1, out, bn);
        k_final<<<g4, 256, 0, stream>>>(out, bn, gamma, beta, pa);
    }
}

// Round 10
// 327.541 us; speedup vs baseline: 7.8139x; 2.0210x over previous
//
#include <hip/hip_runtime.h>
#include <hip/hip_bf16.h>

#define NODES 100000
#define BN_EPS 1e-5f
#define NB2 128          // coarse buckets
#define NPB2 782         // nodes per bucket (128*782 = 100096 >= 100000)
#define CAP 25776        // slots per bucket (avg 25000, +4.9 sigma), 16-aligned
#define EPB 8192         // edges per place block (391 blocks at E=3.2M)

__device__ __forceinline__ unsigned bf16rne(float f) {
    unsigned u = __float_as_uint(f);
    u += 0x7FFFu + ((u >> 16) & 1u);
    return u >> 16;
}
__device__ __forceinline__ float bflo(unsigned u) { return __uint_as_float(u << 16); }
__device__ __forceinline__ float bfhi(unsigned u) { return __uint_as_float(u & 0xFFFF0000u); }

// ---------------------------------------------------------------------------
// init: cursor[b] = b*CAP, bn = 0.
// ---------------------------------------------------------------------------
__global__ __launch_bounds__(256) void k_init(int* __restrict__ cursor,
                                              float* __restrict__ bn) {
    const int t = threadIdx.x;
    if (t < NB2) cursor[t] = t * CAP;
    else if (t < NB2 + 128) bn[t - NB2] = 0.f;
}

// ---------------------------------------------------------------------------
// Placement into capacity-strided buckets (no hist/scan prepass needed).
// ---------------------------------------------------------------------------
__global__ __launch_bounds__(256) void k_place(
        const int* __restrict__ ridx, const int* __restrict__ gidx,
        int* __restrict__ cursor, unsigned* __restrict__ packed, int E) {
    __shared__ int lh[4][NB2];
    const int t = threadIdx.x;
    const int w = t >> 6;
    for (int k = t; k < 4 * NB2; k += 256) ((int*)lh)[k] = 0;
    __syncthreads();
    const int base = blockIdx.x * EPB;
    for (int k = 0; k < EPB / 256; ++k) {
        int e = base + t + k * 256;
        if (e < E) atomicAdd(&lh[w][(unsigned)ridx[e] / NPB2], 1);
    }
    __syncthreads();
    if (t < NB2) {
        int c0 = lh[0][t], c1 = lh[1][t], c2 = lh[2][t], c3 = lh[3][t];
        int tot = c0 + c1 + c2 + c3;
        if (tot) {
            int g0 = atomicAdd(&cursor[t], tot);
            lh[0][t] = g0;
            lh[1][t] = g0 + c0;
            lh[2][t] = g0 + c0 + c1;
            lh[3][t] = g0 + c0 + c1 + c2;
        }
    }
    __syncthreads();
    for (int k = 0; k < EPB / 256; ++k) {
        int e = base + t + k * 256;
        if (e < E) {
            unsigned r = (unsigned)ridx[e];
            unsigned b = r / NPB2;
            int off = atomicAdd(&lh[w][b], 1);
            if (off < (int)((b + 1) * CAP))   // capacity guard (P ~ 4e-5)
                packed[off] = ((r - b * NPB2) << 17) | (unsigned)gidx[e];
        }
    }
}

// ---------------------------------------------------------------------------
// Bucket sort, in place within the bucket's private L2-resident region.
// ---------------------------------------------------------------------------
__global__ __launch_bounds__(1024) void k_sortb(
        const int* __restrict__ cursor, unsigned* __restrict__ packed,
        int* __restrict__ nodestart, int* __restrict__ cnt) {
    __shared__ int lh[1024];
    __shared__ int lsc[1024];
    const int b = blockIdx.x, t = threadIdx.x;
    const int s0b = b * CAP;
    int cntb = cursor[b] - s0b;
    if (cntb > CAP) cntb = CAP;
    unsigned r[(CAP + 1023) / 1024];  // 26, statically indexed
#pragma unroll
    for (int kk = 0; kk < (CAP + 1023) / 1024; ++kk) {
        int k = t + kk * 1024;
        if (k < cntb) r[kk] = packed[s0b + k];
    }
    lh[t] = 0;
    __syncthreads();
#pragma unroll
    for (int kk = 0; kk < (CAP + 1023) / 1024; ++kk) {
        int k = t + kk * 1024;
        if (k < cntb) atomicAdd(&lh[r[kk] >> 17], 1);
    }
    __syncthreads();
    lsc[t] = lh[t];
    __syncthreads();
    for (int off = 1; off < 1024; off <<= 1) {
        int v = lsc[t];
        int add = (t >= off) ? lsc[t - off] : 0;
        __syncthreads();
        lsc[t] = v + add;
        __syncthreads();
    }
    int excl = (t == 0) ? 0 : lsc[t - 1];
    if (t < NPB2) {
        int n = b * NPB2 + t;
        if (n < NODES) {
            nodestart[n] = s0b + excl;
            cnt[n] = lh[t];
        }
    }
    __syncthreads();
    lh[t] = excl;           // becomes scatter cursor
    __syncthreads();
#pragma unroll
    for (int kk = 0; kk < (CAP + 1023) / 1024; ++kk) {
        int k = t + kk * 1024;
        if (k < cntb) {
            unsigned v = r[kk];
            int pos = atomicAdd(&lh[v >> 17], 1);
            packed[s0b + pos] = v & 0x1FFFFu;
        }
    }
}

// ---------------------------------------------------------------------------
// GEMM -> packed-bf16 Fn. 4x4 blocking via ds_read_b128.
// __launch_bounds__(256,4): 128-VGPR cap; unroll 8 bounds the load window
// (round-8/9 lesson: uncapped unroll -> 256 VGPR -> scratch spill storm).
// ---------------------------------------------------------------------------
__global__ __launch_bounds__(256, 4) void k_gemm_bf16(
        const float* __restrict__ x, const float* __restrict__ wn,
        unsigned* __restrict__ Fnh2) {
    __shared__ float lx[64 * 68];   // [ci][j],  row stride 68 (16B-aligned)
    __shared__ float wt[64 * 68];   // [ci][co], transposed weights
    const int t = threadIdx.x;
    const int n0 = blockIdx.x * 64;
    for (int idx = t; idx < 4096; idx += 256) {
        int rr = idx >> 6, q = idx & 63;
        int n = n0 + q;
        lx[rr * 68 + q] = (n < NODES) ? x[rr * NODES + n] : 0.f;
        wt[q * 68 + rr] = wn[idx];   // wn[co=rr][ci=q] -> wt[ci=q][co=rr]
    }
    __syncthreads();
    const int c4 = (t & 15) * 4;    // 4 consecutive output channels
    const int j4 = (t >> 4) * 4;    // 4 consecutive nodes
    float4 a0 = {0,0,0,0}, a1 = {0,0,0,0}, a2 = {0,0,0,0}, a3 = {0,0,0,0};
#pragma unroll 8
    for (int ci = 0; ci < 64; ++ci) {
        float4 w = *(const float4*)&wt[ci * 68 + c4];
        float4 xv = *(const float4*)&lx[ci * 68 + j4];
        a0.x += w.x * xv.x; a0.y += w.x * xv.y; a0.z += w.x * xv.z; a0.w += w.x * xv.w;
        a1.x += w.y * xv.x; a1.y += w.y * xv.y; a1.z += w.y * xv.z; a1.w += w.y * xv.w;
        a2.x += w.z * xv.x; a2.y += w.z * xv.y; a2.z += w.z * xv.z; a2.w += w.z * xv.w;
        a3.x += w.w * xv.x; a3.y += w.w * xv.y; a3.z += w.w * xv.z; a3.w += w.w * xv.w;
    }
    uint2* F2 = (uint2*)Fnh2;
#pragma unroll
    for (int k = 0; k < 4; ++k) {
        int n = n0 + j4 + k;
        if (n < NODES) {
            float v0 = (k == 0) ? a0.x : (k == 1) ? a0.y : (k == 2) ? a0.z : a0.w;
            float v1 = (k == 0) ? a1.x : (k == 1) ? a1.y : (k == 2) ? a1.z : a1.w;
            float v2 = (k == 0) ? a2.x : (k == 1) ? a2.y : (k == 2) ? a2.z : a2.w;
            float v3 = (k == 0) ? a3.x : (k == 1) ? a3.y : (k == 2) ? a3.z : a3.w;
            uint2 val;
            val.x = bf16rne(v0) | (bf16rne(v1) << 16);
            val.y = bf16rne(v2) | (bf16rne(v3) << 16);
            F2[n * 16 + (c4 >> 2)] = val;   // 128B contiguous across 16 lanes
        }
    }
}

// fp32 Fn variant (fallback path only)
__global__ __launch_bounds__(256) void k_gemm_n(
        const float* __restrict__ x, const float* __restrict__ wn,
        float* __restrict__ Fn) {
    __shared__ float lx[64][65];
    __shared__ float lw[64][65];
    const int t = threadIdx.x;
    const int n0 = blockIdx.x * 64;
    for (int idx = t; idx < 4096; idx += 256) {
        int r = idx >> 6, q = idx & 63;
        lw[r][q] = wn[idx];
        int n = n0 + q;
        lx[r][q] = (n < NODES) ? x[r * NODES + n] : 0.f;
    }
    __syncthreads();
    const int c = t & 63;
    const int jb = t >> 6;
    for (int k = 0; k < 16; ++k) {
        int j = jb + 4 * k;
        int n = n0 + j;
        if (n >= NODES) continue;
        float acc = 0.f;
#pragma unroll
        for (int ci = 0; ci < 64; ++ci)
            acc += lw[c][ci] * lx[ci][j];
        Fn[n * 64 + c] = acc;
    }
}

// ---------------------------------------------------------------------------
// Pull segment-mean: one wave per node, 2 edges per gather instruction.
// ---------------------------------------------------------------------------
__global__ __launch_bounds__(256) void k_segreduce(
        const unsigned* __restrict__ Fnh2, const unsigned* __restrict__ packed,
        const int* __restrict__ nodestart, const int* __restrict__ cnt,
        float2* __restrict__ mean2) {
    const int n = (int)((blockIdx.x * 256u + threadIdx.x) >> 6);
    if (n >= NODES) return;
    const int lane = threadIdx.x & 63;
    const int sub = lane >> 5;
    const int cp = lane & 31;
    const int s0 = nodestart[n];
    const int cn = cnt[n];
    const int s1 = s0 + cn;
    float ax = 0.f, ay = 0.f;
    int i = s0;
    for (; i + 7 < s1; i += 8) {
        int g0 = (int)packed[i     + sub];
        int g1 = (int)packed[i + 2 + sub];
        int g2 = (int)packed[i + 4 + sub];
        int g3 = (int)packed[i + 6 + sub];
        unsigned u0 = Fnh2[g0 * 32 + cp];
        unsigned u1 = Fnh2[g1 * 32 + cp];
        unsigned u2 = Fnh2[g2 * 32 + cp];
        unsigned u3 = Fnh2[g3 * 32 + cp];
        ax += bflo(u0) + bflo(u1) + bflo(u2) + bflo(u3);
        ay += bfhi(u0) + bfhi(u1) + bfhi(u2) + bfhi(u3);
    }
    for (; i < s1; i += 2) {
        if (i + sub < s1) {
            unsigned u = Fnh2[(int)packed[i + sub] * 32 + cp];
            ax += bflo(u);
            ay += bfhi(u);
        }
    }
    ax += __shfl_xor(ax, 32);
    ay += __shfl_xor(ay, 32);
    if (sub == 0) {
        float inv = 1.f / fmaxf((float)cn, 1.f);
        float2 m; m.x = ax * inv; m.y = ay * inv;
        mean2[n * 32 + cp] = m;
    }
}

// ---------------------------------------------------------------------------
// Combine: Fv GEMM (4x4, capped regs), + mean, BN partials, LDS transpose.
// tile aliases dead wt buffer. reds/redq padded to 17 (bank-conflict-free).
// ---------------------------------------------------------------------------
__global__ __launch_bounds__(256, 4) void k_combine(
        const float* __restrict__ x, const float* __restrict__ wv,
        const float* __restrict__ sums, const int* __restrict__ counts,
        const int divide,
        float* __restrict__ outpre, float* __restrict__ bn) {
    __shared__ float lx[64 * 68];
    __shared__ float wt[64 * 68];   // reused as tile[c*65+j] after FMA loop
    __shared__ float reds[64][17];
    __shared__ float redq[64][17];
    const int t = threadIdx.x;
    const int n0 = blockIdx.x * 64;
    for (int idx = t; idx < 4096; idx += 256) {
        int rr = idx >> 6, q = idx & 63;
        int n = n0 + q;
        lx[rr * 68 + q] = (n < NODES) ? x[rr * NODES + n] : 0.f;
        wt[q * 68 + rr] = wv[idx];
    }
    __syncthreads();
    const int c4 = (t & 15) * 4;
    const int j4 = (t >> 4) * 4;
    float4 a0 = {0,0,0,0}, a1 = {0,0,0,0}, a2 = {0,0,0,0}, a3 = {0,0,0,0};
#pragma unroll 8
    for (int ci = 0; ci < 64; ++ci) {
        float4 w = *(const float4*)&wt[ci * 68 + c4];
        float4 xv = *(const float4*)&lx[ci * 68 + j4];
        a0.x += w.x * xv.x; a0.y += w.x * xv.y; a0.z += w.x * xv.z; a0.w += w.x * xv.w;
        a1.x += w.y * xv.x; a1.y += w.y * xv.y; a1.z += w.y * xv.z; a1.w += w.y * xv.w;
        a2.x += w.z * xv.x; a2.y += w.z * xv.y; a2.z += w.z * xv.z; a2.w += w.z * xv.w;
        a3.x += w.w * xv.x; a3.y += w.w * xv.y; a3.z += w.w * xv.z; a3.w += w.w * xv.w;
    }
    __syncthreads();                 // wt is dead for ALL waves; reuse as tile
    float* tile = wt;
    float ls0 = 0.f, ls1 = 0.f, ls2 = 0.f, ls3 = 0.f;
    float lq0 = 0.f, lq1 = 0.f, lq2 = 0.f, lq3 = 0.f;
    const float4* sums4 = (const float4*)sums;
#pragma unroll
    for (int k = 0; k < 4; ++k) {
        int j = j4 + k;
        int n = n0 + j;
        float v0 = 0.f, v1 = 0.f, v2 = 0.f, v3 = 0.f;
        if (n < NODES) {
            float4 mv = sums4[n * 16 + (c4 >> 2)];
            if (divide) {
                float cf = fmaxf((float)counts[n], 1.f);
                mv.x /= cf; mv.y /= cf; mv.z /= cf; mv.w /= cf;
            }
            float b0 = (k == 0) ? a0.x : (k == 1) ? a0.y : (k == 2) ? a0.z : a0.w;
            float b1 = (k == 0) ? a1.x : (k == 1) ? a1.y : (k == 2) ? a1.z : a1.w;
            float b2 = (k == 0) ? a2.x : (k == 1) ? a2.y : (k == 2) ? a2.z : a2.w;
            float b3 = (k == 0) ? a3.x : (k == 1) ? a3.y : (k == 2) ? a3.z : a3.w;
            v0 = mv.x + b0; v1 = mv.y + b1; v2 = mv.z + b2; v3 = mv.w + b3;
            ls0 += v0; lq0 += v0 * v0;
            ls1 += v1; lq1 += v1 * v1;
            ls2 += v2; lq2 += v2 * v2;
            ls3 += v3; lq3 += v3 * v3;
        }
        tile[(c4 + 0) * 65 + j] = v0;
        tile[(c4 + 1) * 65 + j] = v1;
        tile[(c4 + 2) * 65 + j] = v2;
        tile[(c4 + 3) * 65 + j] = v3;
    }
    const int jg = t >> 4;
    reds[c4 + 0][jg] = ls0; redq[c4 + 0][jg] = lq0;
    reds[c4 + 1][jg] = ls1; redq[c4 + 1][jg] = lq1;
    reds[c4 + 2][jg] = ls2; redq[c4 + 2][jg] = lq2;
    reds[c4 + 3][jg] = ls3; redq[c4 + 3][jg] = lq3;
    __syncthreads();
    const int j2 = t & 63;
    const int c2 = t >> 6;
    const int n = n0 + j2;
    if (n < NODES) {
        for (int k = 0; k < 16; ++k) {
            int cc = c2 + 4 * k;
            outpre[cc * NODES + n] = tile[cc * 65 + j2];
        }
    }
    if (t < 64) {
        float s = 0.f, q = 0.f;
#pragma unroll
        for (int k = 0; k < 16; ++k) { s += reds[t][k]; q += redq[t][k]; }
        atomicAdd(&bn[t], s);
        atomicAdd(&bn[64 + t], q);
    }
}

// K4: per-channel affine from batch stats + PReLU, in place on d_out [C][N].
__global__ __launch_bounds__(256) void k_final(
        float* __restrict__ out, const float* __restrict__ bn,
        const float* __restrict__ gamma, const float* __restrict__ beta,
        const float* __restrict__ pa) {
    const int c = blockIdx.y;
    const int n = blockIdx.x * 256 + threadIdx.x;
    const float invN = 1.f / (float)NODES;
    float mu = bn[c] * invN;
    float var = fmaxf(bn[64 + c] * invN - mu * mu, 0.f);
    float scale = gamma[c] * rsqrtf(var + BN_EPS);
    float shift = beta[c] - mu * scale;
    float a = pa[0];
    if (n < NODES) {
        float y = out[c * NODES + n] * scale + shift;
        y = (y >= 0.f) ? y : a * y;
        out[c * NODES + n] = y;
    }
}

// Fallback (ws too small): round-2 atomic scatter, proven correct.
__global__ __launch_bounds__(256) void k_scatter(
        const float* __restrict__ Fn,
        const int* __restrict__ gidx, const int* __restrict__ ridx,
        float* __restrict__ sums, int* __restrict__ counts, int E) {
    const int wave = (int)((blockIdx.x * blockDim.x + threadIdx.x) >> 6);
    const int lane = threadIdx.x & 63;
    const int base = wave * 64;
    if (base >= E) return;
    const int nvalid = min(64, E - base);
    int g = 0, r = 0;
    if (lane < nvalid) {
        g = gidx[base + lane];
        r = ridx[base + lane];
        atomicAdd(&counts[r], 1);
    }
    for (int i = 0; i < nvalid; ++i) {
        int gg = __shfl(g, i);
        int rr = __shfl(r, i);
        float v = Fn[gg * 64 + lane];
        atomicAdd(&sums[rr * 64 + lane], v);
    }
}

extern "C" void kernel_launch(void* const* d_in, const int* in_sizes, int n_in,
                              void* d_out, int out_size, void* d_ws, size_t ws_size,
                              hipStream_t stream) {
    const float* x     = (const float*)d_in[0];
    const float* w_v   = (const float*)d_in[1];
    const float* w_n   = (const float*)d_in[2];
    const float* gamma = (const float*)d_in[3];
    const float* beta  = (const float*)d_in[4];
    const float* pa    = (const float*)d_in[5];
    const int* ridx    = (const int*)d_in[6];
    const int* gidx    = (const int*)d_in[7];
    float* out = (float*)d_out;

    const int E = in_sizes[6];
    const long long N64 = (long long)NODES * 64;
    const int ntiles = (NODES + 63) / 64;
    const dim3 g4((NODES + 255) / 256, 64);

    // Main ws (words): mean[N64] | packed[128*CAP] | cursor[128] | bn[128] |
    //                  nodestart[NODES] | cnt[NODES]   = 9,899,584 (39.6 MB)
    size_t need = ((size_t)N64 + (size_t)NB2 * CAP + NB2 + 128
                   + NODES + NODES) * 4;

    if (ws_size >= need) {
        float*    mean      = (float*)d_ws;
        unsigned* packed    = (unsigned*)(mean + N64);
        int*      cursor    = (int*)(packed + (size_t)NB2 * CAP);
        float*    bn        = (float*)(cursor + NB2);
        int*      nodestart = (int*)(bn + 128);
        int*      cntarr    = nodestart + NODES;
        unsigned* Fnh2 = (unsigned*)out;  // 12.8 MB staged in d_out

        k_init<<<1, 256, 0, stream>>>(cursor, bn);
        k_place<<<(E + EPB - 1) / EPB, 256, 0, stream>>>(ridx, gidx, cursor,
                                                         packed, E);
        k_sortb<<<NB2, 1024, 0, stream>>>(cursor, packed, nodestart, cntarr);
        k_gemm_bf16<<<ntiles, 256, 0, stream>>>(x, w_n, Fnh2);
        k_segreduce<<<(NODES * 64 + 255) / 256, 256, 0, stream>>>(
            Fnh2, packed, nodestart, cntarr, (float2*)mean);
        k_combine<<<ntiles, 256, 0, stream>>>(x, w_v, mean, cntarr, 0, out, bn);
        k_final<<<g4, 256, 0, stream>>>(out, bn, gamma, beta, pa);
    } else {
        // Fallback: atomic-scatter path (26.0 MB ws).
        float* sums   = (float*)d_ws;
        int*   counts = (int*)(sums + N64);
        float* bn     = (float*)(sums + N64 + NODES);
        float* Fn = out;

        hipMemsetAsync(sums, 0, (size_t)(N64 + NODES + 128) * sizeof(float),
                       stream);
        k_gemm_n<<<ntiles, 256, 0, stream>>>(x, w_n, Fn);
        k_scatter<<<(E + 255) / 256, 256, 0, stream>>>(Fn, gidx, ridx, sums,
                                                       counts, E);
        k_combine<<<ntiles, 256, 0, stream>>>(x, w_v, sums, counts, 1, out, bn);
        k_final<<<g4, 256, 0, stream>>>(out, bn, gamma, beta, pa);
    }
}